// Round 2
// baseline (1616.610 us; speedup 1.0000x reference)
//
#include <hip/hip_runtime.h>
#include <hip/hip_fp16.h>

typedef _Float16 f16;
typedef _Float16 f16x8 __attribute__((ext_vector_type(8)));
typedef float f32x4 __attribute__((ext_vector_type(4)));

#define B_SZ   4096
#define T_SZ   32
#define VOCAB  10000
#define E_SZ   300
#define H_SZ   300
#define KP     320          // per-operand K padded (10x32)
#define KW     640          // combined [Whh|Wih] row width
#define GP     304          // per-gate padded N (19x16)
#define G4     1216         // 4*GP
#define M_TOT  (B_SZ*T_SZ)  // 131072
#define LDA    328          // LDS row stride f16: 656B = 41x16B -> 2-way bank alias (free)

__device__ __forceinline__ float sigmoid_f(float x) {
    return 1.f / (1.f + __expf(-x));
}
__device__ __forceinline__ float tanh_f(float x) {
    x = fminf(fmaxf(x, -15.f), 15.f);
    float e = __expf(2.f * x);
    return (e - 1.f) / (e + 1.f);
}

// P0: embed_w f32 [V][300] -> embT f16 [V][320] zero-padded
__global__ void kP0(const float* __restrict__ ew, f16* __restrict__ embT) {
    int v = blockIdx.x, k = threadIdx.x;           // 320 threads
    embT[(size_t)v * KP + k] = (k < E_SZ) ? (f16)ew[(size_t)v * E_SZ + k] : (f16)0.f;
}

// PW: Wcat f16 [1216][640]: cols 0..319 = W_hh (padded), cols 320..639 = W_ih (padded); bias sum
__global__ void kPW(const float* __restrict__ wih, const float* __restrict__ whh,
                    const float* __restrict__ bih, const float* __restrict__ bhh,
                    f16* __restrict__ Wcat, float* __restrict__ biasp) {
    int np = blockIdx.x;                           // 0..1215
    int k  = threadIdx.x;                          // 0..319
    int g = np / GP, j = np - g * GP;
    bool valid = (j < H_SZ);
    int src = g * H_SZ + j;
    f16 a = (f16)0.f, b = (f16)0.f;
    if (valid && k < E_SZ) {
        b = (f16)whh[(size_t)src * H_SZ + k];
        a = (f16)wih[(size_t)src * E_SZ + k];
    }
    Wcat[(size_t)np * KW + k]      = b;
    Wcat[(size_t)np * KW + KP + k] = a;
    if (k == 0) biasp[np] = valid ? (bih[src] + bhh[src]) : 0.f;
}

// P2: weight-normed classifier W = g * v / ||v||  -> Wc f32 [2][GP]
__global__ void kP2(const float* __restrict__ cls_v, const float* __restrict__ cls_g,
                    float* __restrict__ Wc) {
    int lane = threadIdx.x;                        // 64
    for (int cl = 0; cl < 2; ++cl) {
        float s = 0.f;
        for (int j = lane; j < H_SZ; j += 64) { float v = cls_v[cl * H_SZ + j]; s += v * v; }
        for (int off = 32; off; off >>= 1) s += __shfl_down(s, off);
        float nrm = sqrtf(__shfl(s, 0));
        float scale = cls_g[cl] / nrm;
        for (int j = lane; j < H_SZ; j += 64) Wc[cl * GP + j] = cls_v[cl * H_SZ + j] * scale;
    }
}

// kA (split path): xg[m][n'] = embT[cap[m]] . Wih[n'] + bias[n'], f16 [131072][1216]
// A-frags direct from global (embT is L2-resident); only B staged in LDS (42.5 KB).
__global__ __launch_bounds__(256) void kA(const int* __restrict__ cap,
                                          const f16* __restrict__ embT,
                                          const f16* __restrict__ Wcat,
                                          const float* __restrict__ biasp,
                                          f16* __restrict__ xg) {
    __shared__ __align__(16) f16 Bs[64 * LDA];
    __shared__ int capv[128];
    int tid = threadIdx.x;
    int m0 = blockIdx.x * 128;
    if (tid < 128) capv[tid] = cap[m0 + tid];
    __syncthreads();
    int wave = tid >> 6, lane = tid & 63;
    int c = lane & 15, q = lane >> 4;
    // A-frags for 2 m-subtiles (wave, wave+4), register-resident across all n-chunks
    f16x8 afr[2][10];
#pragma unroll
    for (int ms = 0; ms < 2; ++ms) {
        int v = capv[(wave + ms * 4) * 16 + c];
#pragma unroll
        for (int k = 0; k < 10; ++k)
            afr[ms][k] = *(const f16x8*)(embT + (size_t)v * KP + k * 32 + q * 8);
    }
    for (int nc = 0; nc < 19; ++nc) {
        __syncthreads();                           // prev chunk's Bs reads done
#pragma unroll
        for (int it = 0; it < 10; ++it) {
            int cc = tid + it * 256;               // 0..2559 = 64 rows x 40 chunks
            int row = cc / 40, c8 = cc - row * 40;
            *(f16x8*)(&Bs[row * LDA + c8 * 8]) =
                *(const f16x8*)(Wcat + (size_t)(nc * 64 + row) * KW + KP + c8 * 8);
        }
        __syncthreads();
#pragma unroll
        for (int nt = 0; nt < 4; ++nt) {
            int ncol = nc * 64 + nt * 16 + c;
            float bia = biasp[ncol];
            f32x4 acc0 = {bia, bia, bia, bia};     // bias is per-n (col=c) -> same all 4 regs
            f32x4 acc1 = {bia, bia, bia, bia};
#pragma unroll
            for (int k = 0; k < 10; ++k) {
                f16x8 bfr = *(const f16x8*)(&Bs[(nt * 16 + c) * LDA + k * 32 + q * 8]);
                acc0 = __builtin_amdgcn_mfma_f32_16x16x32_f16(afr[0][k], bfr, acc0, 0, 0, 0);
                acc1 = __builtin_amdgcn_mfma_f32_16x16x32_f16(afr[1][k], bfr, acc1, 0, 0, 0);
            }
#pragma unroll
            for (int r = 0; r < 4; ++r) {
                xg[(size_t)(m0 + wave * 16 + q * 4 + r) * G4 + ncol] = (f16)acc0[r];
                xg[(size_t)(m0 + (wave + 4) * 16 + q * 4 + r) * G4 + ncol] = (f16)acc1[r];
            }
        }
    }
}

// kRs (split path): persistent recurrence, 256 blocks x 512 thr (8 waves), 16 batch rows.
// Wave w -> gate w>>1, n-halves; h in LDS (single buffer), c-state in registers.
__global__ __launch_bounds__(512) void kRs(const int* __restrict__ cap_len,
                                           const f16* __restrict__ Wcat,
                                           const f16* __restrict__ xg,
                                           float* __restrict__ hlast) {
    __shared__ __align__(16) f16 hbuf[16 * LDA];
    __shared__ f16 gates[4][16 * GP];
    __shared__ int lens[16];
    int tid = threadIdx.x;
    int b0 = blockIdx.x * 16;
    if (tid < 16) lens[tid] = cap_len[b0 + tid];
    for (int i = tid; i < 16 * LDA; i += 512) hbuf[i] = (f16)0.f;  // pads stay 0 forever
    __syncthreads();
    int wave = tid >> 6, lane = tid & 63;
    int c = lane & 15, q = lane >> 4;
    int gate = wave >> 1;
    int ntA = (wave & 1) ? 10 : 0;
    int ntB = (wave & 1) ? 19 : 10;
    const f16* Wg = Wcat + (size_t)(gate * GP) * KW;
    float creg[10];
#pragma unroll
    for (int i = 0; i < 10; ++i) creg[i] = 0.f;
    for (int t = 0; t < T_SZ; ++t) {
        // phase 1: gate preacts = h @ W_hh^T (B-frags streamed straight from L2)
        f16x8 afr[10];
#pragma unroll
        for (int k = 0; k < 10; ++k)
            afr[k] = *(const f16x8*)(&hbuf[c * LDA + k * 32 + q * 8]);
        for (int nt = ntA; nt < ntB; ++nt) {
            f32x4 acc = {0.f, 0.f, 0.f, 0.f};
            const f16* wrow = Wg + (size_t)(nt * 16 + c) * KW + q * 8;
#pragma unroll
            for (int k = 0; k < 10; ++k) {
                f16x8 bfr = *(const f16x8*)(wrow + k * 32);
                acc = __builtin_amdgcn_mfma_f32_16x16x32_f16(afr[k], bfr, acc, 0, 0, 0);
            }
#pragma unroll
            for (int r = 0; r < 4; ++r)
                gates[gate][(q * 4 + r) * GP + nt * 16 + c] = (f16)acc[r];
        }
        __syncthreads();   // also orders afr LDS reads before hbuf writes below
        // phase 2: elementwise cell update; thread's (m,j) slots fixed over time -> c in regs
#pragma unroll
        for (int it = 0; it < 10; ++it) {
            int idx = tid + it * 512;              // 0..5119 = 16*320
            int m = idx / 320, j = idx - m * 320;
            if (j < H_SZ) {
                const f16* xr = xg + (size_t)((b0 + m) * T_SZ + t) * G4;
                float gi = (float)gates[0][m * GP + j] + (float)xr[j];
                float gf = (float)gates[1][m * GP + j] + (float)xr[GP + j];
                float gg = (float)gates[2][m * GP + j] + (float)xr[2 * GP + j];
                float go = (float)gates[3][m * GP + j] + (float)xr[3 * GP + j];
                float ii = sigmoid_f(gi);
                float ff = sigmoid_f(gf);
                float gt = tanh_f(gg);
                float oo = sigmoid_f(go);
                float cn = ff * creg[it] + ii * gt;
                creg[it] = cn;
                float hh = oo * tanh_f(cn);
                hbuf[m * LDA + j] = (f16)hh;
                if (t == lens[m] - 1) hlast[(size_t)(b0 + m) * GP + j] = hh;
            }
        }
        __syncthreads();
    }
}

// kRf (fused fallback, ~13 MB workspace): gates = [h|x] @ [Whh|Wih]^T + bias, per step.
__global__ __launch_bounds__(512) void kRf(const int* __restrict__ cap,
                                           const int* __restrict__ cap_len,
                                           const f16* __restrict__ embT,
                                           const f16* __restrict__ Wcat,
                                           const float* __restrict__ biasp,
                                           float* __restrict__ hlast) {
    __shared__ __align__(16) f16 hbuf[16 * LDA];
    __shared__ f16 gates[4][16 * GP];
    __shared__ int lens[16];
    __shared__ int capv[16 * T_SZ];
    int tid = threadIdx.x;
    int b0 = blockIdx.x * 16;
    if (tid < 16) lens[tid] = cap_len[b0 + tid];
    capv[tid] = cap[(size_t)b0 * T_SZ + tid];      // [m][t] row-major, 512 ints
    for (int i = tid; i < 16 * LDA; i += 512) hbuf[i] = (f16)0.f;
    __syncthreads();
    int wave = tid >> 6, lane = tid & 63;
    int c = lane & 15, q = lane >> 4;
    int gate = wave >> 1;
    int ntA = (wave & 1) ? 10 : 0;
    int ntB = (wave & 1) ? 19 : 10;
    const f16* Wg = Wcat + (size_t)(gate * GP) * KW;
    float creg[10];
#pragma unroll
    for (int i = 0; i < 10; ++i) creg[i] = 0.f;
    for (int t = 0; t < T_SZ; ++t) {
        f16x8 afr[10], afx[10];
        int v = capv[c * T_SZ + t];
#pragma unroll
        for (int k = 0; k < 10; ++k) {
            afr[k] = *(const f16x8*)(&hbuf[c * LDA + k * 32 + q * 8]);
            afx[k] = *(const f16x8*)(embT + (size_t)v * KP + k * 32 + q * 8);
        }
        for (int nt = ntA; nt < ntB; ++nt) {
            float bia = biasp[gate * GP + nt * 16 + c];
            f32x4 acc = {bia, bia, bia, bia};
            const f16* wrow = Wg + (size_t)(nt * 16 + c) * KW + q * 8;
#pragma unroll
            for (int k = 0; k < 10; ++k)
                acc = __builtin_amdgcn_mfma_f32_16x16x32_f16(
                    afr[k], *(const f16x8*)(wrow + k * 32), acc, 0, 0, 0);
#pragma unroll
            for (int k = 0; k < 10; ++k)
                acc = __builtin_amdgcn_mfma_f32_16x16x32_f16(
                    afx[k], *(const f16x8*)(wrow + KP + k * 32), acc, 0, 0, 0);
#pragma unroll
            for (int r = 0; r < 4; ++r)
                gates[gate][(q * 4 + r) * GP + nt * 16 + c] = (f16)acc[r];
        }
        __syncthreads();
#pragma unroll
        for (int it = 0; it < 10; ++it) {
            int idx = tid + it * 512;
            int m = idx / 320, j = idx - m * 320;
            if (j < H_SZ) {
                float gi = (float)gates[0][m * GP + j];
                float gf = (float)gates[1][m * GP + j];
                float gg = (float)gates[2][m * GP + j];
                float go = (float)gates[3][m * GP + j];
                float ii = sigmoid_f(gi);
                float ff = sigmoid_f(gf);
                float gt = tanh_f(gg);
                float oo = sigmoid_f(go);
                float cn = ff * creg[it] + ii * gt;
                creg[it] = cn;
                float hh = oo * tanh_f(cn);
                hbuf[m * LDA + j] = (f16)hh;
                if (t == lens[m] - 1) hlast[(size_t)(b0 + m) * GP + j] = hh;
            }
        }
        __syncthreads();
    }
}

// kC: out[row][cl] = hlast[row] . Wc[cl] + cls_b[cl]
__global__ void kC(const float* __restrict__ hlast, const float* __restrict__ Wc,
                   const float* __restrict__ cls_b, float* __restrict__ out) {
    int row = blockIdx.x, lane = threadIdx.x;      // 64 threads
    const float* h = hlast + (size_t)row * GP;
    float s0 = 0.f, s1 = 0.f;
    for (int j = lane; j < H_SZ; j += 64) {
        float hv = h[j];
        s0 += hv * Wc[j];
        s1 += hv * Wc[GP + j];
    }
    for (int off = 32; off; off >>= 1) {
        s0 += __shfl_down(s0, off);
        s1 += __shfl_down(s1, off);
    }
    if (lane == 0) {
        out[row * 2 + 0] = s0 + cls_b[0];
        out[row * 2 + 1] = s1 + cls_b[1];
    }
}

extern "C" void kernel_launch(void* const* d_in, const int* in_sizes, int n_in,
                              void* d_out, int out_size, void* d_ws, size_t ws_size,
                              hipStream_t stream) {
    const int*   cap     = (const int*)d_in[0];
    const int*   cap_len = (const int*)d_in[1];
    const float* embed_w = (const float*)d_in[2];
    const float* W_ih    = (const float*)d_in[3];
    const float* W_hh    = (const float*)d_in[4];
    const float* b_ih    = (const float*)d_in[5];
    const float* b_hh    = (const float*)d_in[6];
    const float* cls_v   = (const float*)d_in[7];
    const float* cls_g   = (const float*)d_in[8];
    const float* cls_b   = (const float*)d_in[9];
    float* out = (float*)d_out;

    char* w = (char*)d_ws;
    size_t off = 0;
    auto alloc = [&](size_t bytes) -> void* {
        void* p = w + off;
        off += (bytes + 255) & ~(size_t)255;
        return p;
    };
    // small buffers first (identical placement in both paths)
    f16*   embT  = (f16*)alloc((size_t)VOCAB * KP * sizeof(f16));    // 6.4 MB
    f16*   Wcat  = (f16*)alloc((size_t)G4 * KW * sizeof(f16));       // 1.56 MB
    float* biasp = (float*)alloc((size_t)G4 * sizeof(float));
    float* Wc    = (float*)alloc((size_t)2 * GP * sizeof(float));
    float* hlast = (float*)alloc((size_t)B_SZ * GP * sizeof(float)); // 5.0 MB
    size_t xg_bytes = (size_t)M_TOT * G4 * sizeof(f16);              // 304 MiB
    bool split = (ws_size >= off + xg_bytes);                        // deterministic per run
    f16* xg = (f16*)(w + off);

    kP0<<<VOCAB, KP, 0, stream>>>(embed_w, embT);
    kPW<<<G4, KP, 0, stream>>>(W_ih, W_hh, b_ih, b_hh, Wcat, biasp);
    kP2<<<1, 64, 0, stream>>>(cls_v, cls_g, Wc);
    if (split) {
        kA<<<M_TOT / 128, 256, 0, stream>>>(cap, embT, Wcat, biasp, xg);
        kRs<<<B_SZ / 16, 512, 0, stream>>>(cap_len, Wcat, xg, hlast);
    } else {
        kRf<<<B_SZ / 16, 512, 0, stream>>>(cap, cap_len, embT, Wcat, biasp, hlast);
    }
    kC<<<B_SZ, 64, 0, stream>>>(hlast, Wc, cls_b, out);
}